// Round 9
// baseline (210.909 us; speedup 1.0000x reference)
//
#include <hip/hip_runtime.h>

#define HW (1024 * 1024)
#define PLANE 8388608   // C * 128 * 128 = 512 * 16384

typedef _Float16 half4 __attribute__((ext_vector_type(4)));
typedef _Float16 half8 __attribute__((ext_vector_type(8)));
typedef float floatx4 __attribute__((ext_vector_type(4)));

// Single fused kernel: one block per image ROW y.
//  1. stage row y's 7 input channels (f32) -> LDS fp16  (each input byte read ONCE
//     from HBM — the old kernel A and its 16 MB G round-trip are deleted)
//  2. stage cent (4 KB) + c (12 KB) into LDS; scan the 512 windows for
//     cy0 <= y < cy0+128 via 2 tests/thread + LDS-atomic compaction
//  3. each wave processes every 4th intersecting window (~16/wave, Binomial
//     sigma/mu ~12% -> balanced, unlike R3's ragged 32x32 tiles):
//     the verified R8 inner body (C-folded MFMA pair), B-fragments from LDS.
// Traffic: 28 MB reads + 134 MB compulsory writes (was 296 MB total + 2 launches).
__global__ __launch_bounds__(256) void instanseg_row(
    const float* __restrict__ x,      // (6, 1024, 1024)
    const float* __restrict__ sigma,  // (1, 1024, 1024)
    const float* __restrict__ c,      // (512, 6)
    const float* __restrict__ W1,     // (7, 16)
    const float* __restrict__ b1,     // (16)
    const float* __restrict__ W2,     // (16, 16)
    const float* __restrict__ b2,     // (16)
    const float* __restrict__ W3,     // (16, 1)
    const float* __restrict__ b3,     // (1)
    const int*   __restrict__ cent,   // (512, 2)
    float* __restrict__ out)
{
    __shared__ _Float16 rowG[1024 * 8];   // 16 KB: row pixels x 8 fp16 channels
    __shared__ float    cs[512 * 6];      // 12 KB
    __shared__ int      centS[1024];      //  4 KB
    __shared__ int      wlist[512];       //  2 KB
    __shared__ int      wcount;

    const int y   = blockIdx.x;
    const int tid = threadIdx.x;

    if (tid == 0) wcount = 0;

    // ---- stage cent + c (coalesced) ----
    for (int i = tid; i < 1024; i += 256) centS[i] = cent[i];
    for (int i = tid; i < 3072; i += 256) cs[i] = c[i];

    // ---- stage row y: f32 -> fp16, channel-padded to 8 ----
#pragma unroll
    for (int p4 = 0; p4 < 4; ++p4) {
        const int px = p4 * 256 + tid;
        half8 g;
#pragma unroll
        for (int e = 0; e < 6; ++e) g[e] = (_Float16)x[e * HW + y * 1024 + px];
        g[6] = (_Float16)sigma[y * 1024 + px];
        g[7] = (_Float16)0.0f;
        *(half8*)&rowG[px * 8] = g;
    }
    __syncthreads();

    // ---- scan: windows whose 128-row span covers row y ----
    for (int w = tid; w < 512; w += 256) {
        const int cy0 = min(max(centS[2 * w], 64), 960) - 64;
        if (y >= cy0 && y < cy0 + 128)
            wlist[atomicAdd(&wcount, 1)] = w;
    }
    __syncthreads();
    const int nw = wcount;
    if (nw == 0) return;   // block-uniform

    const int lane = tid & 63, wave = tid >> 6;
    const int quad = lane >> 4, sub = lane & 15;

    // window-independent fragments/constants (verified R8 layout)
    // MFMA1 A: A[m=sub][k=4q+i] = W1[k][sub] (0 for k>=7)
    half4 a1, a2;
    float w3f[4], b1r[4], w1n[6][4];
    floatx4 cb;
#pragma unroll
    for (int i = 0; i < 4; ++i) {
        const int k = 4 * quad + i;
        a1[i]  = (k < 7) ? (_Float16)W1[k * 16 + sub] : (_Float16)0.0f;
        a2[i]  = (_Float16)W2[k * 16 + sub];
        w3f[i] = W3[k];
        cb[i]  = b2[k];
        b1r[i] = b1[k];
#pragma unroll
        for (int e = 0; e < 6; ++e) w1n[e][i] = W1[e * 16 + k];
    }
    const float b3v = b3[0];

    // ---- per intersecting window (wave-striped) ----
    for (int wi = wave; wi < nw; wi += 4) {
        const int cid = wlist[wi];
        const int cy0 = min(max(centS[2 * cid], 64), 960) - 64;
        const int cx0 = min(max(centS[2 * cid + 1], 64), 960) - 64;

        // cq = b1 - W1^T c[cid]  (layer-1 offset, folded into MFMA1's C-operand)
        floatx4 cq;
#pragma unroll
        for (int i = 0; i < 4; ++i) {
            float qv = b1r[i];
#pragma unroll
            for (int e = 0; e < 6; ++e)
                qv = fmaf(-w1n[e][i], cs[cid * 6 + e], qv);
            cq[i] = qv;
        }

        const int orow = (y - cy0) * 128;   // this row's offset in the window plane

#pragma unroll
        for (int f = 0; f < 2; ++f) {       // two 64-px fragments cover the row
            float logit[4];
#pragma unroll
            for (int ch = 0; ch < 4; ++ch) {
                // B-fragment: quads 0-1 carry channels k=0..7; 2-3 stay zero
                half4 v = (half4)(_Float16)0.0f;
                if (quad < 2)
                    v = *(const half4*)&rowG[(cx0 + f * 64 + ch * 16 + sub) * 8 + quad * 4];

                floatx4 c1 = __builtin_amdgcn_mfma_f32_16x16x16f16(a1, v, cq, 0, 0, 0);
                half4 h;
#pragma unroll
                for (int i = 0; i < 4; ++i)
                    h[i] = (_Float16)fmaxf(c1[i], 0.0f);
                floatx4 c2 = __builtin_amdgcn_mfma_f32_16x16x16f16(a2, h, cb, 0, 0, 0);

                float part = 0.0f;
#pragma unroll
                for (int i = 0; i < 4; ++i)
                    part = fmaf(w3f[i], fmaxf(c2[i], 0.0f), part);
                part += __shfl_xor(part, 16, 64);
                part += __shfl_xor(part, 32, 64);
                logit[ch] = part;
            }

            const float l01 = (quad & 1) ? logit[1] : logit[0];
            const float l23 = (quad & 1) ? logit[3] : logit[2];
            const float lg  = (quad & 2) ? l23 : l01;      // = logit[quad]
            const float prob = 1.0f / (1.0f + __expf(-(lg + b3v)));

            const int n = cid * 16384 + orow + f * 64 + lane;
            out[n]             = prob;
            out[PLANE + n]     = (float)cid;
            out[2 * PLANE + n] = (float)y;
            out[3 * PLANE + n] = (float)(cx0 + f * 64 + lane);
        }
    }
}

extern "C" void kernel_launch(void* const* d_in, const int* in_sizes, int n_in,
                              void* d_out, int out_size, void* d_ws, size_t ws_size,
                              hipStream_t stream) {
    const float* x     = (const float*)d_in[0];
    const float* sigma = (const float*)d_in[1];
    const float* c     = (const float*)d_in[2];
    const float* W1    = (const float*)d_in[3];
    const float* b1    = (const float*)d_in[4];
    const float* W2    = (const float*)d_in[5];
    const float* b2    = (const float*)d_in[6];
    const float* W3    = (const float*)d_in[7];
    const float* b3    = (const float*)d_in[8];
    const int*   cent  = (const int*)d_in[9];
    float* out = (float*)d_out;
    (void)d_ws; (void)ws_size;

    instanseg_row<<<dim3(1024), dim3(256), 0, stream>>>(
        x, sigma, c, W1, b1, W2, b2, W3, b3, cent, out);
}

// Round 10
// 198.546 us; speedup vs baseline: 1.0623x; 1.0623x over previous
//
#include <hip/hip_runtime.h>

#define WS 128
#define HW (1024 * 1024)
#define PLANE 8388608   // C * WS * WS = 512 * 16384

typedef _Float16 half4 __attribute__((ext_vector_type(4)));
typedef _Float16 half8 __attribute__((ext_vector_type(8)));
typedef float floatx4 __attribute__((ext_vector_type(4)));

// Kernel A: G[px][e] = fp16(xs[e][px]) for e<7, 0 pad at e=7.  16 B/px.
__global__ __launch_bounds__(256) void precompute_G(
    const float* __restrict__ x,      // (6, 1024, 1024)
    const float* __restrict__ sigma,  // (1, 1024, 1024)
    _Float16* __restrict__ G)         // (1024*1024, 8)
{
    const int px = blockIdx.x * 256 + threadIdx.x;
    half8 g;
#pragma unroll
    for (int e = 0; e < 6; ++e) g[e] = (_Float16)x[e * HW + px];
    g[6] = (_Float16)sigma[px];
    g[7] = (_Float16)0.0f;
    *(half8*)(G + (size_t)px * 8) = g;
}

// Kernel B: R7 structure (2-stage pipeline, grid (8,512)) with the whole MLP on
// the matrix pipe:
//   c1 = W1^T g + (b1 - W1^T c)   (MFMA1, C-operand fold)
//   h  = relu(c1) -> fp16          [C-layout == B-fragment layout]
//   c2 = W2^T h + b2               (MFMA2, C-operand fold)
//   h2 = relu(c2) -> fp16
//   d3 = w3 . h2 + b3              (MFMA3: A rows all = w3 -> every lane's D3
//                                   holds the COMPLETE logit of its column px)
// MFMA3 replaces the per-fragment pair of dependent __shfl_xor DS round-trips
// (R9's counters showed the kernel is dependency-stall-bound: VALU 52%, MFMA 8%,
// all pipes idle once traffic is minimized) — DS ops/iter 8 -> 0, serial chain
// per fragment shortened ~120 cyc.  3-stage rotate from R8 dropped (regressed).
__global__ __launch_bounds__(256) void instanseg_mlp(
    const _Float16* __restrict__ G,   // (1024*1024, 8)
    const float* __restrict__ c,      // (512, 6)
    const float* __restrict__ W1,     // (7, 16)
    const float* __restrict__ b1,     // (16)
    const float* __restrict__ W2,     // (16, 16)
    const float* __restrict__ b2,     // (16)
    const float* __restrict__ W3,     // (16, 1)
    const float* __restrict__ b3,     // (1)
    const int*   __restrict__ cent,   // (512, 2)
    float* __restrict__ out)
{
    const int cid  = blockIdx.y;
    const int lane = threadIdx.x & 63;
    const int wave = threadIdx.x >> 6;
    const int quad = lane >> 4;
    const int sub  = lane & 15;

    const int cy = min(max(cent[2 * cid], 64), 960);
    const int cx = min(max(cent[2 * cid + 1], 64), 960);
    const int cy0 = cy - 64, cx0 = cx - 64;

    // MFMA1 A-fragment: a1[i] = W1[k][sub], k=4q+i (0 for k >= 7)
    half4 a1;
#pragma unroll
    for (int i = 0; i < 4; ++i) {
        const int k = 4 * quad + i;
        a1[i] = (k < 7) ? (_Float16)W1[k * 16 + sub] : (_Float16)0.0f;
    }

    // MFMA2 A-fragment, MFMA3 A-fragment (w3 broadcast across columns),
    // C-operands: cq = b1 - W1^T c[cid], cb = b2, cb3 = b3.
    half4 a2, a3;
    floatx4 cq, cb, cb3;
#pragma unroll
    for (int i = 0; i < 4; ++i) {
        const int k = 4 * quad + i;
        a2[i] = (_Float16)W2[k * 16 + sub];
        a3[i] = (_Float16)W3[k];          // independent of sub: A rows all = w3
        cb[i] = b2[k];
        float qv = b1[k];
#pragma unroll
        for (int e = 0; e < 6; ++e)
            qv = fmaf(-W1[e * 16 + k], c[cid * 6 + e], qv);
        cq[i] = qv;
    }
    const float b3v = b3[0];
    cb3[0] = b3v; cb3[1] = b3v; cb3[2] = b3v; cb3[3] = b3v;
    const float cidf = (float)cid;

    const int wavestart = blockIdx.x * 2048 + wave * 512;

    // ---- 2-stage pipelined gather (quads 0-1 carry data; 2-3 stay zero,
    //      required: MFMA1 B-fragment rows k>=8 must be zero) ----
    half4 v[4], vn[4];
#pragma unroll
    for (int ch = 0; ch < 4; ++ch) { v[ch] = (half4)(_Float16)0.0f; vn[ch] = (half4)(_Float16)0.0f; }
    {
        // wavestart % 512 == 0 -> one contiguous row segment per wave-iter
        const int base = (cy0 + (wavestart >> 7)) * 1024 + cx0 + sub;
        const _Float16* rowp = G + (size_t)base * 8 + quad * 4;
        if (quad < 2) {
#pragma unroll
            for (int ch = 0; ch < 4; ++ch)
                v[ch] = *(const half4*)(rowp + ch * 128);   // 16 px * 8 ch
        }
    }

#pragma unroll
    for (int it = 0; it < 8; ++it) {
        const int start = wavestart + it * 64;

        if (it < 7) {   // batch-issue next iteration's 4 fragment loads
            const int nstart = start + 64;
            const int base = (cy0 + (nstart >> 7)) * 1024 + cx0 + (nstart & 127) + sub;
            const _Float16* rowp = G + (size_t)base * 8 + quad * 4;
            if (quad < 2) {
#pragma unroll
                for (int ch = 0; ch < 4; ++ch)
                    vn[ch] = *(const half4*)(rowp + ch * 128);
            }
        }

        float d3v[4];
#pragma unroll
        for (int ch = 0; ch < 4; ++ch) {
            // layer 1, offset folded into C
            floatx4 c1 = __builtin_amdgcn_mfma_f32_16x16x16f16(a1, v[ch], cq, 0, 0, 0);
            half4 h;
#pragma unroll
            for (int i = 0; i < 4; ++i)
                h[i] = (_Float16)fmaxf(c1[i], 0.0f);      // RNE cvt (verified path)

            // layer 2, b2 folded into C
            floatx4 c2 = __builtin_amdgcn_mfma_f32_16x16x16f16(a2, h, cb, 0, 0, 0);
            half4 h2;
#pragma unroll
            for (int i = 0; i < 4; ++i)
                h2[i] = (_Float16)fmaxf(c2[i], 0.0f);

            // layer 3: every lane's d3 = w3 . h2(col sub) + b3 (all 4 regs equal)
            floatx4 d3 = __builtin_amdgcn_mfma_f32_16x16x16f16(a3, h2, cb3, 0, 0, 0);
            d3v[ch] = d3[0];
        }

        // lane (quad,sub) owns pixel start + quad*16 + sub -> take ch == quad
        const float l01 = (quad & 1) ? d3v[1] : d3v[0];
        const float l23 = (quad & 1) ? d3v[3] : d3v[2];
        const float lg  = (quad & 2) ? l23 : l01;
        const float prob = 1.0f / (1.0f + __expf(-lg));   // b3 already folded

        const int rowy = cy0 + (start >> 7);              // wave-uniform
        const int colx = cx0 + (start & 127) + lane;
        const int n    = cid * 16384 + start + lane;
        out[n]             = prob;
        out[PLANE + n]     = cidf;
        out[2 * PLANE + n] = (float)rowy;
        out[3 * PLANE + n] = (float)colx;

        if (it < 7) {
#pragma unroll
            for (int ch = 0; ch < 4; ++ch) v[ch] = vn[ch];
        }
    }
}

extern "C" void kernel_launch(void* const* d_in, const int* in_sizes, int n_in,
                              void* d_out, int out_size, void* d_ws, size_t ws_size,
                              hipStream_t stream) {
    const float* x     = (const float*)d_in[0];
    const float* sigma = (const float*)d_in[1];
    const float* c     = (const float*)d_in[2];
    const float* W1    = (const float*)d_in[3];
    const float* b1    = (const float*)d_in[4];
    const float* W2    = (const float*)d_in[5];
    const float* b2    = (const float*)d_in[6];
    const float* W3    = (const float*)d_in[7];
    const float* b3    = (const float*)d_in[8];
    const int*   cent  = (const int*)d_in[9];
    float* out = (float*)d_out;
    _Float16* G = (_Float16*)d_ws;   // 1024*1024*8 fp16 = 16 MB scratch

    precompute_G<<<dim3(HW / 256), dim3(256), 0, stream>>>(x, sigma, G);
    instanseg_mlp<<<dim3(8, 512), dim3(256), 0, stream>>>(
        G, c, W1, b1, W2, b2, W3, b3, cent, out);
}

// Round 11
// 197.959 us; speedup vs baseline: 1.0654x; 1.0030x over previous
//
#include <hip/hip_runtime.h>

#define WS 128
#define HW (1024 * 1024)
#define PLANE 8388608   // C * WS * WS = 512 * 16384

typedef _Float16 half4 __attribute__((ext_vector_type(4)));
typedef _Float16 half8 __attribute__((ext_vector_type(8)));
typedef float floatx4 __attribute__((ext_vector_type(4)));

// Kernel A: G[px][e] = fp16(xs[e][px]) for e<7, 0 pad at e=7.  16 B/px.
__global__ __launch_bounds__(256) void precompute_G(
    const float* __restrict__ x,      // (6, 1024, 1024)
    const float* __restrict__ sigma,  // (1, 1024, 1024)
    _Float16* __restrict__ G)         // (1024*1024, 8)
{
    const int px = blockIdx.x * 256 + threadIdx.x;
    half8 g;
#pragma unroll
    for (int e = 0; e < 6; ++e) g[e] = (_Float16)x[e * HW + px];
    g[6] = (_Float16)sigma[px];
    g[7] = (_Float16)0.0f;
    *(half8*)(G + (size_t)px * 8) = g;
}

// Kernel B: EXACT R7 body (best measured, 192.7) with ONE delta: nontemporal
// output stores.  R7's B writes 134 MB/iter that is never read; flowing it
// through L2/L3 evicts the 16 MB G array that B's 8x-overlapped 134 MB of
// reads depend on, forcing HBM re-fetches.  NT was only ever tested in the
// byte-bound regime (R2) / bad grid (R4) — never isolated on the post-R5
// L3-residency-dependent structure (same regime-shift logic that turned the
// R2-null pipeline into R7's -8 us win).
// R8's C-folds and R10's MFMA3 epilogue are both reverted (each regressed).
__global__ __launch_bounds__(256) void instanseg_mlp(
    const _Float16* __restrict__ G,   // (1024*1024, 8)
    const float* __restrict__ c,      // (512, 6)
    const float* __restrict__ W1,     // (7, 16)
    const float* __restrict__ b1,     // (16)
    const float* __restrict__ W2,     // (16, 16)
    const float* __restrict__ b2,     // (16)
    const float* __restrict__ W3,     // (16, 1)
    const float* __restrict__ b3,     // (1)
    const int*   __restrict__ cent,   // (512, 2)
    float* __restrict__ out)
{
    const int cid  = blockIdx.y;
    const int lane = threadIdx.x & 63;
    const int wave = threadIdx.x >> 6;
    const int quad = lane >> 4;
    const int sub  = lane & 15;

    const int cy = min(max(cent[2 * cid], 64), 960);
    const int cx = min(max(cent[2 * cid + 1], 64), 960);
    const int cy0 = cy - 64, cx0 = cx - 64;

    // MFMA1 A-fragment: A[m=sub][k=4*quad+i] = W1[k][sub] (0 for k >= 7)
    half4 a1;
#pragma unroll
    for (int i = 0; i < 4; ++i) {
        const int k = 4 * quad + i;
        a1[i] = (k < 7) ? (_Float16)W1[k * 16 + sub] : (_Float16)0.0f;
    }

    // MFMA2 A-fragment + f32 layer-1 offset q and layer-2/3 constants
    half4 a2;
    float w3f[4], bb2[4], qf[4];
#pragma unroll
    for (int i = 0; i < 4; ++i) {
        const int k = 4 * quad + i;
        a2[i]  = (_Float16)W2[k * 16 + sub];
        w3f[i] = W3[k];
        bb2[i] = b2[k];
        float qv = -b1[k];
#pragma unroll
        for (int e = 0; e < 6; ++e)
            qv = fmaf(W1[e * 16 + k], c[cid * 6 + e], qv);
        qf[i] = qv;
    }
    const float b3v = b3[0];
    const floatx4 zero = {0.0f, 0.0f, 0.0f, 0.0f};

    const int wavestart = blockIdx.x * 2048 + wave * 512;

    // ---- 2-stage pipelined gather (quads 0-1 carry data; 2-3 stay zero,
    //      required: MFMA1 B-fragment rows k>=8 must be zero) ----
    half4 v[4], vn[4];
#pragma unroll
    for (int ch = 0; ch < 4; ++ch) { v[ch] = (half4)(_Float16)0.0f; vn[ch] = (half4)(_Float16)0.0f; }
    {
        // wavestart % 512 == 0 -> one contiguous row segment per wave-iter
        const int base = (cy0 + (wavestart >> 7)) * 1024 + cx0 + sub;
        const _Float16* rowp = G + (size_t)base * 8 + quad * 4;
        if (quad < 2) {
#pragma unroll
            for (int ch = 0; ch < 4; ++ch)
                v[ch] = *(const half4*)(rowp + ch * 128);   // 16 px * 8 ch
        }
    }

    for (int it = 0; it < 8; ++it) {
        const int start = wavestart + it * 64;

        if (it < 7) {   // batch-issue next iteration's 4 fragment loads
            const int nstart = start + 64;
            const int base = (cy0 + (nstart >> 7)) * 1024 + cx0 + (nstart & 127) + sub;
            const _Float16* rowp = G + (size_t)base * 8 + quad * 4;
            if (quad < 2) {
#pragma unroll
                for (int ch = 0; ch < 4; ++ch)
                    vn[ch] = *(const half4*)(rowp + ch * 128);
            }
        }

        float logit[4];
#pragma unroll
        for (int ch = 0; ch < 4; ++ch) {
            // layer 1 on the matrix pipe
            floatx4 c1 = __builtin_amdgcn_mfma_f32_16x16x16f16(a1, v[ch], zero, 0, 0, 0);

            // h = relu(c1 - q), single fp16 rounding — C-layout == B-layout
            half4 h;
#pragma unroll
            for (int i = 0; i < 4; ++i)
                h[i] = (_Float16)fmaxf(c1[i] - qf[i], 0.0f);

            // layer 2 on the matrix pipe
            floatx4 c2 = __builtin_amdgcn_mfma_f32_16x16x16f16(a2, h, zero, 0, 0, 0);

            float part = 0.0f;
#pragma unroll
            for (int i = 0; i < 4; ++i)
                part = fmaf(w3f[i], fmaxf(c2[i] + bb2[i], 0.0f), part);
            part += __shfl_xor(part, 16, 64);
            part += __shfl_xor(part, 32, 64);
            logit[ch] = part;
        }

        const float l01 = (quad & 1) ? logit[1] : logit[0];
        const float l23 = (quad & 1) ? logit[3] : logit[2];
        const float lg  = (quad & 2) ? l23 : l01;
        const float prob = 1.0f / (1.0f + __expf(-(lg + b3v)));

        const int rowy = cy0 + (start >> 7);            // wave-uniform
        const int colx = cx0 + (start & 127) + lane;
        const int n    = cid * 16384 + start + lane;
        __builtin_nontemporal_store(prob,         out + n);
        __builtin_nontemporal_store((float)cid,   out + PLANE + n);
        __builtin_nontemporal_store((float)rowy,  out + 2 * PLANE + n);
        __builtin_nontemporal_store((float)colx,  out + 3 * PLANE + n);

        if (it < 7) {
#pragma unroll
            for (int ch = 0; ch < 4; ++ch) v[ch] = vn[ch];
        }
    }
}

extern "C" void kernel_launch(void* const* d_in, const int* in_sizes, int n_in,
                              void* d_out, int out_size, void* d_ws, size_t ws_size,
                              hipStream_t stream) {
    const float* x     = (const float*)d_in[0];
    const float* sigma = (const float*)d_in[1];
    const float* c     = (const float*)d_in[2];
    const float* W1    = (const float*)d_in[3];
    const float* b1    = (const float*)d_in[4];
    const float* W2    = (const float*)d_in[5];
    const float* b2    = (const float*)d_in[6];
    const float* W3    = (const float*)d_in[7];
    const float* b3    = (const float*)d_in[8];
    const int*   cent  = (const int*)d_in[9];
    float* out = (float*)d_out;
    _Float16* G = (_Float16*)d_ws;   // 1024*1024*8 fp16 = 16 MB scratch

    precompute_G<<<dim3(HW / 256), dim3(256), 0, stream>>>(x, sigma, G);
    instanseg_mlp<<<dim3(8, 512), dim3(256), 0, stream>>>(
        G, c, W1, b1, W2, b2, W3, b3, cent, out);
}